// Round 1
// baseline (89.168 us; speedup 1.0000x reference)
//
#include <hip/hip_runtime.h>

typedef __bf16 bf16x8 __attribute__((ext_vector_type(8)));
typedef float  f32x4  __attribute__((ext_vector_type(4)));

#define TILE_M 128
#define TILE_N 128
#define TILE_K 64

constexpr int NB = 32;    // batch
constexpr int TT = 2048;  // context rows
constexpr int JJ = 512;   // question rows
constexpr int DD = 256;   // feature dim

__global__ __launch_bounds__(256)
void sim_mfma_kernel(const float* __restrict__ ctx,
                     const float* __restrict__ que,
                     const float* __restrict__ wvec,
                     float* __restrict__ out)
{
    __shared__ __align__(16) unsigned char sA[TILE_M * TILE_K * 2];
    __shared__ __align__(16) unsigned char sB[TILE_N * TILE_K * 2];
    __shared__ float c_s[TILE_M];
    __shared__ float q_s[TILE_N];

    const int tid = threadIdx.x;
    const int l   = tid & 63;
    const int wid = tid >> 6;          // wave 0..3
    const int wm0 = (wid >> 1) * 64;   // wave row offset in tile
    const int wn0 = (wid & 1) * 64;    // wave col offset in tile

    const int n0 = blockIdx.x * TILE_N;
    const int m0 = blockIdx.y * TILE_M;
    const int bI = blockIdx.z;

    const float* wc = wvec;            // w[0:256]
    const float* wq = wvec + DD;       // w[256:512]
    const float* wm = wvec + 2 * DD;   // w[512:768]

    if (tid < TILE_M) { c_s[tid] = 0.f; q_s[tid] = 0.f; }

    f32x4 acc[4][4];
    const f32x4 vzero = {0.f, 0.f, 0.f, 0.f};
    #pragma unroll
    for (int m = 0; m < 4; ++m)
      #pragma unroll
      for (int n = 0; n < 4; ++n) acc[m][n] = vzero;

    const int g  = tid & 7;    // k-group (8 f32 each)
    const int r0 = tid >> 3;   // base row 0..31

    for (int ks = 0; ks < DD / TILE_K; ++ks) {
        __syncthreads();   // LDS free (prev compute done); c_s/q_s zeroed before 1st iter
        const int kg = ks * TILE_K + g * 8;

        float wmv[8], wcv[8], wqv[8];
        #pragma unroll
        for (int i = 0; i < 8; ++i) { wmv[i] = wm[kg + i]; wcv[i] = wc[kg + i]; wqv[i] = wq[kg + i]; }

        #pragma unroll
        for (int p = 0; p < 4; ++p) {
            const int row = r0 + p * 32;

            // ---- A tile: context * wm  (also accumulate c_term partial with wc)
            const float* srcA = ctx + ((size_t)(bI * TT + m0 + row)) * DD + kg;
            f32x4 a0 = *(const f32x4*)(srcA);
            f32x4 a1 = *(const f32x4*)(srcA + 4);
            float av[8] = {a0[0], a0[1], a0[2], a0[3], a1[0], a1[1], a1[2], a1[3]};
            bf16x8 pkA;
            float cp = 0.f;
            #pragma unroll
            for (int i = 0; i < 8; ++i) {
                pkA[i] = (__bf16)(av[i] * wmv[i]);
                cp += av[i] * wcv[i];
            }
            cp += __shfl_xor(cp, 1);
            cp += __shfl_xor(cp, 2);
            cp += __shfl_xor(cp, 4);
            int byteA = row * (TILE_K * 2) + g * 16;
            byteA ^= (row & 7) << 4;                 // T2 swizzle (16B slots)
            *(bf16x8*)(sA + byteA) = pkA;
            if (g == 0) c_s[row] += cp;              // single writer per row per step

            // ---- B tile: question (also accumulate q_term partial with wq)
            const float* srcB = que + ((size_t)(bI * JJ + n0 + row)) * DD + kg;
            f32x4 b0 = *(const f32x4*)(srcB);
            f32x4 b1 = *(const f32x4*)(srcB + 4);
            float bvv[8] = {b0[0], b0[1], b0[2], b0[3], b1[0], b1[1], b1[2], b1[3]};
            bf16x8 pkB;
            float qp = 0.f;
            #pragma unroll
            for (int i = 0; i < 8; ++i) {
                pkB[i] = (__bf16)(bvv[i]);
                qp += bvv[i] * wqv[i];
            }
            qp += __shfl_xor(qp, 1);
            qp += __shfl_xor(qp, 2);
            qp += __shfl_xor(qp, 4);
            int byteB = row * (TILE_K * 2) + g * 16;
            byteB ^= (row & 7) << 4;
            *(bf16x8*)(sB + byteB) = pkB;
            if (g == 0) q_s[row] += qp;
        }
        __syncthreads();

        // ---- compute: 2 k-frags (K=32 each) x 4x4 fragments
        #pragma unroll
        for (int kk = 0; kk < 2; ++kk) {
            const int kb = kk * 64 + (l >> 4) * 16;   // byte offset of this lane's k-slice
            bf16x8 af[4], bfr[4];
            #pragma unroll
            for (int m = 0; m < 4; ++m) {
                const int row = wm0 + m * 16 + (l & 15);
                int byteA = row * (TILE_K * 2) + kb;
                byteA ^= (row & 7) << 4;
                af[m] = *(const bf16x8*)(sA + byteA);
            }
            #pragma unroll
            for (int n = 0; n < 4; ++n) {
                const int row = wn0 + n * 16 + (l & 15);
                int byteB = row * (TILE_K * 2) + kb;
                byteB ^= (row & 7) << 4;
                bfr[n] = *(const bf16x8*)(sB + byteB);
            }
            #pragma unroll
            for (int m = 0; m < 4; ++m)
              #pragma unroll
              for (int n = 0; n < 4; ++n)
                acc[m][n] = __builtin_amdgcn_mfma_f32_16x16x32_bf16(af[m], bfr[n], acc[m][n], 0, 0, 0);
        }
    }

    // ---- epilogue: D lane mapping col=l&15, row=(l>>4)*4+q
    const int lr = l & 15;
    const int lq = (l >> 4) * 4;
    #pragma unroll
    for (int m = 0; m < 4; ++m) {
        const int rowL = wm0 + m * 16 + lq;
        #pragma unroll
        for (int n = 0; n < 4; ++n) {
            const int colL = wn0 + n * 16 + lr;
            const float qv = q_s[colL];
            float* dst = out + ((size_t)(bI * TT + m0 + rowL)) * JJ + (n0 + colL);
            const f32x4 v = acc[m][n];
            #pragma unroll
            for (int q = 0; q < 4; ++q)
                dst[(size_t)q * JJ] = v[q] + c_s[rowL + q] + qv;
        }
    }
}

extern "C" void kernel_launch(void* const* d_in, const int* in_sizes, int n_in,
                              void* d_out, int out_size, void* d_ws, size_t ws_size,
                              hipStream_t stream) {
    (void)in_sizes; (void)n_in; (void)d_ws; (void)ws_size; (void)out_size;
    const float* ctx = (const float*)d_in[0];
    const float* que = (const float*)d_in[1];
    const float* wv  = (const float*)d_in[2];
    float* out = (float*)d_out;

    dim3 grid(JJ / TILE_N, TT / TILE_M, NB);   // 4 x 16 x 32 = 2048 blocks
    sim_mfma_kernel<<<grid, dim3(256), 0, stream>>>(ctx, que, wv, out);
}

// Round 2
// 86.491 us; speedup vs baseline: 1.0310x; 1.0310x over previous
//
#include <hip/hip_runtime.h>
#include <stdint.h>

typedef __bf16 bf16x8 __attribute__((ext_vector_type(8)));
typedef float  f32x4  __attribute__((ext_vector_type(4)));

typedef __attribute__((address_space(1))) const void g_void;
typedef __attribute__((address_space(3))) void l_void;

constexpr int NB = 32, TT = 2048, JJ = 512, DD = 256;
constexpr int BM = 128, BN = 128, BK = 32;
constexpr int KSTEPS = DD / BK;   // 8

// LDS map (bytes):
//   sA   [    0, 16384)  f32[128][32], row stride 128 B, 16-B chunks, chunk' = c ^ (row&7)
//   sB   [16384, 32768)  same layout
//   w_s  [32768, 35840)  768 f32 (wc | wq | wm)
//   c_s  [35840, 36352)  128 f32
//   q_s  [36352, 36864)  128 f32

__global__ __launch_bounds__(256)
void sim_kernel(const float* __restrict__ ctx, const float* __restrict__ que,
                const float* __restrict__ wvec, float* __restrict__ out)
{
    __shared__ __align__(1024) unsigned char lds[36864];
    float* w_s = (float*)(lds + 32768);
    float* c_s = (float*)(lds + 35840);
    float* q_s = (float*)(lds + 36352);

    const int tid = threadIdx.x;
    const int l   = tid & 63;
    const int wid = tid >> 6;

    // XCD-aware block swizzle: 2048 blocks, 8 XCDs -> each XCD gets 256
    // consecutive work-ids (A-tile sharers + whole batches co-XCD).
    const int pb = blockIdx.x;
    const int id = (pb & 7) * 256 + (pb >> 3);
    const int n0 = (id & 3) * BN;
    const int m0 = ((id >> 2) & 15) * BM;
    const int bI = id >> 6;

    // small-LDS init (visible after first __syncthreads)
    if (tid < 192) *(f32x4*)(w_s + tid * 4) = *(const f32x4*)(wvec + tid * 4);
    if (tid < 128) { c_s[tid] = 0.f; q_s[tid] = 0.f; }

    // ---- async staging geometry: wave0->A rows0-63, wave1->A rows64-127,
    //      wave2->B rows0-63, wave3->B rows64-127. 8 issues/thread/step.
    const int rsub = l >> 3;      // row within 8-row group
    const int csub = l & 7;       // LDS chunk slot
    const int regionRow0 = (wid & 1) * 64;
    const bool isA = (wid < 2);
    const float* srcBase = isA
        ? (ctx + ((size_t)bI * TT + m0 + regionRow0) * DD)
        : (que + ((size_t)bI * JJ + n0 + regionRow0) * DD);
    // source chunk pre-swizzled: data for LDS slot (r,c) comes from global chunk c^(r&7); r&7 == rsub
    const float* lane_src = srcBase + (size_t)rsub * DD + ((csub ^ rsub) << 2);
    unsigned char* ldsRegion = lds + (isA ? 0 : 16384) + regionRow0 * 128;

    auto stage = [&](int ks) {
        const float* s = lane_src + ks * BK;
        #pragma unroll
        for (int i = 0; i < 8; ++i)
            __builtin_amdgcn_global_load_lds((g_void*)(s + (size_t)i * 8 * DD),
                                             (l_void*)(ldsRegion + i * 1024), 16, 0, 0);
    };

    stage(0);

    f32x4 acc[4][4];
    #pragma unroll
    for (int m = 0; m < 4; ++m)
        #pragma unroll
        for (int n = 0; n < 4; ++n) acc[m][n] = f32x4{0.f, 0.f, 0.f, 0.f};

    const int wm_0 = (wid >> 1) * 64;   // wave row offset
    const int wn_0 = (wid & 1) * 64;    // wave col offset
    const int lr = l & 15;
    const int ksl = (l >> 4) * 8;       // this lane's k-slice start within BK
    const int c0  = (l >> 4) * 2;       // chunk pair index

    const bool doC = ((wid & 1) == 0);  // waves 0,2 own c_term rows
    const bool doQ = (wid < 2);         // waves 0,1 own q_term cols

    for (int ks = 0; ks < KSTEPS; ++ks) {
        __syncthreads();   // vmcnt(0) drain: DMA of tile ks complete

        f32x4 wmA = *(f32x4*)(w_s + 512 + ks * BK + ksl);
        f32x4 wmB = *(f32x4*)(w_s + 512 + ks * BK + ksl + 4);
        f32x4 wqA, wqB, wcA, wcB;
        if (doQ) { wqA = *(f32x4*)(w_s + 256 + ks * BK + ksl);
                   wqB = *(f32x4*)(w_s + 256 + ks * BK + ksl + 4); }
        if (doC) { wcA = *(f32x4*)(w_s + ks * BK + ksl);
                   wcB = *(f32x4*)(w_s + ks * BK + ksl + 4); }

        bf16x8 af[4], bfr[4];

        // ---- B fragments (raw f32 -> bf16) + q_term partials
        #pragma unroll
        for (int n = 0; n < 4; ++n) {
            const int r  = wn_0 + n * 16 + lr;
            const int sw = r & 7;
            const unsigned char* rp = lds + 16384 + r * 128;
            f32x4 x0 = *(const f32x4*)(rp + ((c0 ^ sw) << 4));
            f32x4 x1 = *(const f32x4*)(rp + (((c0 + 1) ^ sw) << 4));
            bf16x8 pk;
            #pragma unroll
            for (int i = 0; i < 4; ++i) { pk[i] = (__bf16)x0[i]; pk[4 + i] = (__bf16)x1[i]; }
            bfr[n] = pk;
            if (doQ) {
                float qp = x0[0]*wqA[0] + x0[1]*wqA[1] + x0[2]*wqA[2] + x0[3]*wqA[3]
                         + x1[0]*wqB[0] + x1[1]*wqB[1] + x1[2]*wqB[2] + x1[3]*wqB[3];
                qp += __shfl_xor(qp, 16);
                qp += __shfl_xor(qp, 32);
                if (l < 16) q_s[wn_0 + n * 16 + l] += qp;   // unique writer per col
            }
        }

        // ---- A fragments (raw f32 * wm -> bf16) + c_term partials
        #pragma unroll
        for (int m = 0; m < 4; ++m) {
            const int r  = wm_0 + m * 16 + lr;
            const int sw = r & 7;
            const unsigned char* rp = lds + r * 128;
            f32x4 x0 = *(const f32x4*)(rp + ((c0 ^ sw) << 4));
            f32x4 x1 = *(const f32x4*)(rp + (((c0 + 1) ^ sw) << 4));
            bf16x8 pk;
            #pragma unroll
            for (int i = 0; i < 4; ++i) {
                pk[i]     = (__bf16)(x0[i] * wmA[i]);
                pk[4 + i] = (__bf16)(x1[i] * wmB[i]);
            }
            af[m] = pk;
            if (doC) {
                float cp = x0[0]*wcA[0] + x0[1]*wcA[1] + x0[2]*wcA[2] + x0[3]*wcA[3]
                         + x1[0]*wcB[0] + x1[1]*wcB[1] + x1[2]*wcB[2] + x1[3]*wcB[3];
                cp += __shfl_xor(cp, 16);
                cp += __shfl_xor(cp, 32);
                if (l < 16) c_s[wm_0 + m * 16 + l] += cp;   // unique writer per row
            }
        }

        __syncthreads();   // all reads of tile ks done -> safe to overwrite
        if (ks + 1 < KSTEPS) stage(ks + 1);   // DMA flight overlaps MFMA below + other blocks

        #pragma unroll
        for (int m = 0; m < 4; ++m)
            #pragma unroll
            for (int n = 0; n < 4; ++n)
                acc[m][n] = __builtin_amdgcn_mfma_f32_16x16x32_bf16(af[m], bfr[n], acc[m][n], 0, 0, 0);
    }

    // ---- epilogue: D lane mapping col=l&15, row=(l>>4)*4+q
    const int lq = (l >> 4) * 4;
    #pragma unroll
    for (int m = 0; m < 4; ++m) {
        const int rowL = wm_0 + m * 16 + lq;
        const f32x4 cv = *(f32x4*)(c_s + rowL);
        #pragma unroll
        for (int n = 0; n < 4; ++n) {
            const int colL = wn_0 + n * 16 + lr;
            const float qv = q_s[colL];
            float* dst = out + ((size_t)bI * TT + m0 + rowL) * JJ + (n0 + colL);
            const f32x4 v = acc[m][n];
            #pragma unroll
            for (int q = 0; q < 4; ++q)
                dst[(size_t)q * JJ] = v[q] + cv[q] + qv;
        }
    }
}

extern "C" void kernel_launch(void* const* d_in, const int* in_sizes, int n_in,
                              void* d_out, int out_size, void* d_ws, size_t ws_size,
                              hipStream_t stream) {
    (void)in_sizes; (void)n_in; (void)d_ws; (void)ws_size; (void)out_size;
    const float* ctx = (const float*)d_in[0];
    const float* que = (const float*)d_in[1];
    const float* wv  = (const float*)d_in[2];
    float* out = (float*)d_out;

    sim_kernel<<<dim3(2048), dim3(256), 0, stream>>>(ctx, que, wv, out);
}